// Round 17
// baseline (39.297 us; speedup 1.0000x reference)
//
#include <hip/hip_runtime.h>

// Problem constants (from reference setup_inputs)
#define B_  4
#define H_  64
#define W_  64
#define C_  16
#define F_  32

#define NWE (8 * 9 * F_)   // 2304 weight entries; each = 2 h2 (wt, wk) = 8 B
#define NXE (3 * 34 * 4)   // 408 x-stage chunks (4 channels each)

typedef _Float16 h2 __attribute__((ext_vector_type(2)));

__device__ __forceinline__ h2 pack2(float a, float b) {
    h2 r; r.x = (_Float16)a; r.y = (_Float16)b; return r;
}

// acc += m.x + m.y (f32 accumulate of a packed f16 pair)
__device__ __forceinline__ float acc_dot2(h2 m, float c) {
#if __has_builtin(__builtin_amdgcn_fdot2)
    h2 one; one.x = (_Float16)1.0f; one.y = (_Float16)1.0f;
    return __builtin_amdgcn_fdot2(m, one, c, false);
#else
    return c + (float)m.x + (float)m.y;
#endif
}

// ROUND 17 = DIAGNOSTIC. Exactly the round-13 champion kernel, but the grid
// is replicated 4x (bidx = blockIdx.x & 511): all 4 replicas compute and
// write IDENTICAL values to the same out locations (benign, deterministic).
// Purpose: the single dispatch becomes ~4x16us > the harness's ~39us fills,
// so mtp_main finally appears in the rocprof top-5 WITH COUNTERS after 11
// blind rounds. Next round reverts to the fast grid and acts on the data.
__global__ __launch_bounds__(256) void mtp_main(const float* __restrict__ x,
                                                const float* __restrict__ kern,
                                                const float* __restrict__ tker,
                                                float* __restrict__ out) {
    __shared__ h2 wlds[NWE * 2];        // [ccp(8)][q(9)][f(32)][{wt,wk}]  18432 B
    __shared__ h2 xlds[3][34][8];       // [row][padded col][ch pair]       3264 B

    const int tid  = threadIdx.x;
    const int bidx = blockIdx.x & 511;  // DIAGNOSTIC: 4 replicas of the 512-block grid
    const int half = bidx & 1;
    const int i    = (bidx >> 1) & 63;
    const int b    = bidx >> 7;

    // ---- stage weights (f32 -> packed f16): consecutive tid = consecutive f
    #pragma unroll
    for (int e0 = 0; e0 < 9; ++e0) {
        int e   = e0 * 256 + tid;       // 2304 = 9*256 exactly
        int f   = e & 31;
        int t   = e >> 5;
        int q   = t % 9;
        int ccp = t / 9;
        int s0 = (q * C_ + ccp * 2 + 0) * F_ + f;
        int s1 = (q * C_ + ccp * 2 + 1) * F_ + f;
        wlds[e * 2 + 0] = pack2(tker[s0], tker[s1]);   // wt = times (slope)
        wlds[e * 2 + 1] = pack2(kern[s0], kern[s1]);   // wk = plus (offset)
    }
    // ---- stage x halo (zero-padded, f32 -> packed f16) ----
    for (int e = tid; e < NXE; e += 256) {
        int cc4 = e & 3;
        int t   = e >> 2;
        int cl  = t % 34;               // local padded col
        int di  = t / 34;
        int ro  = i + di - 1;
        int co  = half * 32 + cl - 1;
        float4 v = make_float4(0.f, 0.f, 0.f, 0.f);
        if (ro >= 0 && ro < H_ && co >= 0 && co < W_)
            v = *reinterpret_cast<const float4*>(
                    x + ((b * H_ + ro) * W_ + co) * C_ + cc4 * 4);
        xlds[di][cl][cc4 * 2 + 0] = pack2(v.x, v.y);
        xlds[di][cl][cc4 * 2 + 1] = pack2(v.z, v.w);
    }
    __syncthreads();

    const int lane = tid & 63;
    const int f    = lane & 31;
    const int ps   = lane >> 5;
    const int w    = tid >> 6;          // wave 0..3
    const int cb   = w * 8 + ps;        // padded-col base for lc=0

    float acc[4][4];                    // [it][r]
    #pragma unroll
    for (int it = 0; it < 4; ++it)
        #pragma unroll
        for (int r = 0; r < 4; ++r) acc[it][r] = 0.f;

    #pragma unroll 1
    for (int cc = 0; cc < 8; ++cc) {
        // weights: 9 x 8B (wt,wk adjacent -> merged ds_read)
        h2 wt[9], wk[9];
        #pragma unroll
        for (int q = 0; q < 9; ++q) {
            int bi = ((cc * 9 + q) * F_ + f) * 2;
            wt[q] = wlds[bi];
            wk[q] = wlds[bi + 1];
        }
        // x halo: 3 rows x 9 cols, 4B each (2 distinct addrs/wave -> broadcast)
        h2 xh[3][9];
        #pragma unroll
        for (int dr = 0; dr < 3; ++dr)
            #pragma unroll
            for (int lc = 0; lc < 9; ++lc)
                xh[dr][lc] = xlds[dr][cb + lc][cc];

        #pragma unroll
        for (int it = 0; it < 4; ++it) {
            #pragma unroll
            for (int r = 0; r < 4; ++r) {
                h2 z[9];
                #pragma unroll
                for (int q = 0; q < 9; ++q) {
                    const int a = q / 3, bq = q % 3;
                    int di, dj;
                    switch (r) {   // x position = rot_r^{-1}(weight position q)
                        case 0:  di = a;      dj = bq;     break;
                        case 1:  di = 2 - bq; dj = a;      break;
                        case 2:  di = 2 - a;  dj = 2 - bq; break;
                        default: di = bq;     dj = 2 - a;  break;
                    }
                    // v_pk_fma_f16 via fp-contract on packed mul+add
                    z[q] = xh[di][it * 2 + dj] * wt[q] + wk[q];
                }
                h2 m1 = __builtin_elementwise_max(__builtin_elementwise_max(z[0], z[1]), z[2]);
                h2 m2 = __builtin_elementwise_max(__builtin_elementwise_max(z[3], z[4]), z[5]);
                h2 m3 = __builtin_elementwise_max(__builtin_elementwise_max(z[6], z[7]), z[8]);
                h2 mm = __builtin_elementwise_max(__builtin_elementwise_max(m1, m2), m3);
                acc[it][r] = acc_dot2(mm, acc[it][r]);   // f32 accumulate
            }
        }
    }

    // ---- store: out[b, r, i, jg + it*2, f]; all replicas write identical data
    const int jg = half * 32 + w * 8 + ps;
    #pragma unroll
    for (int r = 0; r < 4; ++r) {
        float* op = out + ((((b * 4 + r) * H_ + i) * W_ + jg) * F_ + f);
        #pragma unroll
        for (int it = 0; it < 4; ++it)
            op[it * 2 * F_] = acc[it][r];
    }
}

extern "C" void kernel_launch(void* const* d_in, const int* in_sizes, int n_in,
                              void* d_out, int out_size, void* d_ws, size_t ws_size,
                              hipStream_t stream) {
    const float* x    = (const float*)d_in[0];
    const float* kern = (const float*)d_in[1];
    const float* tker = (const float*)d_in[2];
    float* out = (float*)d_out;

    // DIAGNOSTIC grid: 4x replication (2048 blocks) to surface counters.
    hipLaunchKernelGGL(mtp_main, dim3(B_ * H_ * 2 * 4), dim3(256), 0, stream,
                       x, kern, tker, out);
}

// Round 18
// 18.017 us; speedup vs baseline: 2.1811x; 2.1811x over previous
//
#include <hip/hip_runtime.h>

// Problem constants (from reference setup_inputs)
#define B_  4
#define H_  64
#define W_  64
#define C_  16
#define F_  32

#define NWE (8 * 9 * F_)   // 2304 weight entries; each = 2 h2 (wt, wk) = 8 B
#define NXE (3 * 34 * 4)   // 408 x-stage chunks (4 channels each)

typedef _Float16 h2 __attribute__((ext_vector_type(2)));

__device__ __forceinline__ h2 pack2(float a, float b) {
    h2 r; r.x = (_Float16)a; r.y = (_Float16)b; return r;
}

// acc += m.x + m.y (f32 accumulate of a packed f16 pair)
__device__ __forceinline__ float acc_dot2(h2 m, float c) {
#if __has_builtin(__builtin_amdgcn_fdot2)
    h2 one; one.x = (_Float16)1.0f; one.y = (_Float16)1.0f;
    return __builtin_amdgcn_fdot2(m, one, c, false);
#else
    return c + (float)m.x + (float)m.y;
#endif
}

// Round-18 = round-13 champion with the 4 rotations SPLIT across 2 blocks
// (grid 512 -> 1024) to double resident blocks/CU (2 -> 4). r17's diagnostic
// showed the same kernel at high blocks/CU runs 9.8us/work vs 16.9 at 2/CU
// (VALUBusy 65%, no conflicts, no spill) -> occupancy/ramp is the binding
// constraint, not VALU/DS counts. RBASE is compile-time (template + block-
// uniform branch) so xh register indexing stays static.
template<int RBASE>
__device__ __forceinline__ void run_compute(const h2* __restrict__ wlds,
                                            const h2 (* __restrict__ xlds)[34][8],
                                            int cb, int f, float acc[4][2]) {
    #pragma unroll 1
    for (int cc = 0; cc < 8; ++cc) {
        // weights: 9 x 8B (wt,wk adjacent -> merged ds_read)
        h2 wt[9], wk[9];
        #pragma unroll
        for (int q = 0; q < 9; ++q) {
            int bi = ((cc * 9 + q) * F_ + f) * 2;
            wt[q] = wlds[bi];
            wk[q] = wlds[bi + 1];
        }
        // x halo: 3 rows x 9 cols, 4B each (2 distinct addrs/wave -> broadcast)
        h2 xh[3][9];
        #pragma unroll
        for (int dr = 0; dr < 3; ++dr)
            #pragma unroll
            for (int lc = 0; lc < 9; ++lc)
                xh[dr][lc] = xlds[dr][cb + lc][cc];

        #pragma unroll
        for (int it = 0; it < 4; ++it) {
            #pragma unroll
            for (int rr = 0; rr < 2; ++rr) {
                const int r = RBASE * 2 + rr;        // compile-time (unrolled)
                h2 z[9];
                #pragma unroll
                for (int q = 0; q < 9; ++q) {
                    const int a = q / 3, bq = q % 3;
                    int di, dj;
                    switch (r) {   // x position = rot_r^{-1}(weight position q)
                        case 0:  di = a;      dj = bq;     break;
                        case 1:  di = 2 - bq; dj = a;      break;
                        case 2:  di = 2 - a;  dj = 2 - bq; break;
                        default: di = bq;     dj = 2 - a;  break;
                    }
                    z[q] = xh[di][it * 2 + dj] * wt[q] + wk[q];   // v_pk_fma_f16
                }
                h2 m1 = __builtin_elementwise_max(__builtin_elementwise_max(z[0], z[1]), z[2]);
                h2 m2 = __builtin_elementwise_max(__builtin_elementwise_max(z[3], z[4]), z[5]);
                h2 m3 = __builtin_elementwise_max(__builtin_elementwise_max(z[6], z[7]), z[8]);
                h2 mm = __builtin_elementwise_max(__builtin_elementwise_max(m1, m2), m3);
                acc[it][rr] = acc_dot2(mm, acc[it][rr]);   // f32 accumulate
            }
        }
    }
}

__global__ __launch_bounds__(256) void mtp_main(const float* __restrict__ x,
                                                const float* __restrict__ kern,
                                                const float* __restrict__ tker,
                                                float* __restrict__ out) {
    __shared__ h2 wlds[NWE * 2];        // [ccp(8)][q(9)][f(32)][{wt,wk}]  18432 B
    __shared__ h2 xlds[3][34][8];       // [row][padded col][ch pair]       3264 B

    const int tid   = threadIdx.x;
    const int bidx  = blockIdx.x;       // (((b*64 + i)*2 + half)*2 + rpair)
    const int rpair = bidx & 1;         // rotation pair: {0,1} or {2,3}
    const int half  = (bidx >> 1) & 1;
    const int i     = (bidx >> 2) & 63;
    const int b     = bidx >> 8;

    // ---- stage weights (f32 -> packed f16): consecutive tid = consecutive f
    #pragma unroll
    for (int e0 = 0; e0 < 9; ++e0) {
        int e   = e0 * 256 + tid;       // 2304 = 9*256 exactly
        int f   = e & 31;
        int t   = e >> 5;
        int q   = t % 9;
        int ccp = t / 9;
        int s0 = (q * C_ + ccp * 2 + 0) * F_ + f;
        int s1 = (q * C_ + ccp * 2 + 1) * F_ + f;
        wlds[e * 2 + 0] = pack2(tker[s0], tker[s1]);   // wt = times (slope)
        wlds[e * 2 + 1] = pack2(kern[s0], kern[s1]);   // wk = plus (offset)
    }
    // ---- stage x halo (zero-padded, f32 -> packed f16) ----
    for (int e = tid; e < NXE; e += 256) {
        int cc4 = e & 3;
        int t   = e >> 2;
        int cl  = t % 34;               // local padded col
        int di  = t / 34;
        int ro  = i + di - 1;
        int co  = half * 32 + cl - 1;
        float4 v = make_float4(0.f, 0.f, 0.f, 0.f);
        if (ro >= 0 && ro < H_ && co >= 0 && co < W_)
            v = *reinterpret_cast<const float4*>(
                    x + ((b * H_ + ro) * W_ + co) * C_ + cc4 * 4);
        xlds[di][cl][cc4 * 2 + 0] = pack2(v.x, v.y);
        xlds[di][cl][cc4 * 2 + 1] = pack2(v.z, v.w);
    }
    __syncthreads();

    const int lane = tid & 63;
    const int f    = lane & 31;
    const int ps   = lane >> 5;
    const int w    = tid >> 6;          // wave 0..3
    const int cb   = w * 8 + ps;        // padded-col base for lc=0

    float acc[4][2];                    // [it][rr]
    #pragma unroll
    for (int it = 0; it < 4; ++it) { acc[it][0] = 0.f; acc[it][1] = 0.f; }

    if (rpair == 0)                     // block-uniform branch; RBASE compile-time
        run_compute<0>(wlds, xlds, cb, f, acc);
    else
        run_compute<1>(wlds, xlds, cb, f, acc);

    // ---- store: out[b, r, i, jg + it*2, f]; per (rr,it) wave stores 256B
    const int jg = half * 32 + w * 8 + ps;
    #pragma unroll
    for (int rr = 0; rr < 2; ++rr) {
        const int r = rpair * 2 + rr;
        float* op = out + ((((b * 4 + r) * H_ + i) * W_ + jg) * F_ + f);
        #pragma unroll
        for (int it = 0; it < 4; ++it)
            op[it * 2 * F_] = acc[it][rr];
    }
}

extern "C" void kernel_launch(void* const* d_in, const int* in_sizes, int n_in,
                              void* d_out, int out_size, void* d_ws, size_t ws_size,
                              hipStream_t stream) {
    const float* x    = (const float*)d_in[0];
    const float* kern = (const float*)d_in[1];
    const float* tker = (const float*)d_in[2];
    float* out = (float*)d_out;

    hipLaunchKernelGGL(mtp_main, dim3(B_ * H_ * 2 * 2), dim3(256), 0, stream,
                       x, kern, tker, out);
}